// Round 6
// baseline (1961.675 us; speedup 1.0000x reference)
//
#include <hip/hip_runtime.h>
#include <math.h>

#define BATCH 4096
#define D 784
#define N 10000

#define KP 800                 // padded K (halves)
#define BK 32                  // K-step (halves)
#define KT (KP / BK)           // 25
#define BM 128
#define BN 128
#define NPAD 10240
#define MARGIN 3.0f

typedef __attribute__((ext_vector_type(8))) short bh8;
typedef __attribute__((ext_vector_type(4))) float fx4;
typedef const __attribute__((address_space(1))) void CGV;
typedef __attribute__((address_space(3))) void LDSV;

static __device__ __forceinline__ unsigned short f2bf(float f) {
    unsigned u = __float_as_uint(f);
    unsigned r = u + 0x7fffu + ((u >> 16) & 1u);
    return (unsigned short)(r >> 16);
}

static __device__ __forceinline__ void top2_insert(float w, int j, float& v0, int& i0,
                                                   float& v1, int& i1) {
    if (w < v0 || (w == v0 && j < i0)) { v1 = v0; i1 = i0; v0 = w; i0 = j; }
    else if (w < v1 || (w == v1 && j < i1)) { v1 = w; i1 = j; }
}

// ---------------------------------------------------------------------------
__global__ __launch_bounds__(256) void convert_x_kernel(const float* __restrict__ x,
                                                        unsigned short* __restrict__ xh) {
    int row = blockIdx.x;
    const float4* xr = (const float4*)(x + (size_t)row * D);
    unsigned short* dst = xh + (size_t)row * KP;
    for (int i = threadIdx.x; i < KP / 4; i += 256) {
        int k = i * 4;
        uint2 o;
        if (k < D) {
            float4 v = xr[i];
            o.x = (unsigned)f2bf(v.x) | ((unsigned)f2bf(v.y) << 16);
            o.y = (unsigned)f2bf(v.z) | ((unsigned)f2bf(v.w) << 16);
        } else { o.x = 0u; o.y = 0u; }
        *(uint2*)(dst + k) = o;
    }
}

__global__ __launch_bounds__(256) void convert_w_kernel(const float* __restrict__ w,
                                                        unsigned short* __restrict__ wh,
                                                        float* __restrict__ wsq) {
    int row = blockIdx.x;
    unsigned short* dst = wh + (size_t)row * KP;
    float s = 0.f;
    if (row < N) {
        const float4* wr = (const float4*)(w + (size_t)row * D);
        for (int i = threadIdx.x; i < KP / 4; i += 256) {
            int k = i * 4;
            uint2 o;
            if (k < D) {
                float4 v = wr[i];
                s += v.x * v.x + v.y * v.y + v.z * v.z + v.w * v.w;
                o.x = (unsigned)f2bf(v.x) | ((unsigned)f2bf(v.y) << 16);
                o.y = (unsigned)f2bf(v.z) | ((unsigned)f2bf(v.w) << 16);
            } else { o.x = 0u; o.y = 0u; }
            *(uint2*)(dst + k) = o;
        }
    } else {
        for (int i = threadIdx.x; i < KP / 4; i += 256) {
            uint2 o; o.x = 0u; o.y = 0u;
            *(uint2*)(dst + i * 4) = o;
        }
    }
    __shared__ float sred[4];
    #pragma unroll
    for (int off = 32; off; off >>= 1) s += __shfl_down(s, off);
    if ((threadIdx.x & 63) == 0) sred[threadIdx.x >> 6] = s;
    __syncthreads();
    if (threadIdx.x == 0) {
        float t = sred[0] + sred[1] + sred[2] + sred[3];
        wsq[row] = (row < N) ? t : INFINITY;
    }
}

// ---------------------------------------------------------------------------
// ABLATION kernel. MODE 0: full ring (round-5). MODE 1: stage-only.
// MODE 2: stage-only, all blocks read the SAME 410 KB (L2-hot probe).
// MODE 3: full GEMM, reg-staged (global->reg->ds_write), compiler waits.
// All write into the scratch/partial region; the real result comes from
// dist_r3_kernel which runs after and overwrites the region rescore reads.
// ---------------------------------------------------------------------------
template <int MODE>
__global__ __launch_bounds__(256, 3) void dist_ablate_kernel(
    const unsigned short* __restrict__ xh, const unsigned short* __restrict__ wh,
    const float* __restrict__ wsq, float4* __restrict__ partial,
    int gx, int cpb) {
    constexpr int NBUF = (MODE == 3) ? 2 : 3;
    __shared__ __align__(16) unsigned short As[NBUF][BM * BK];
    __shared__ __align__(16) unsigned short Bs[NBUF][BM * BK];
    __shared__ float4 red[BM][2];

    const int tid = threadIdx.x;
    const int lane = tid & 63;
    const int wid = tid >> 6;
    const int waveM = (wid >> 1) * 64;
    const int waveN = (wid & 1) * 64;

    const int L = blockIdx.x + gx * blockIdx.y;
    const int xcd = L & 7;
    const int sg = L >> 3;
    const int bx = sg >> 2;
    const int by = xcd * 4 + (sg & 3);
    const int rowBase = (MODE == 2) ? 0 : by * BM;
    const int colBase0 = (MODE == 2) ? 0 : bx * (cpb * BN);

    const int rr = tid >> 2;
    const int csw = (tid & 3) ^ ((rr >> 1) & 3);
    const unsigned short* aSrc0 = xh + (size_t)(rowBase + rr) * KP + csw * 8;
    const unsigned short* aSrc1 = aSrc0 + (size_t)64 * KP;

    char* const ldsA = (char*)&As[0][0] + wid * 1024;
    char* const ldsB = (char*)&Bs[0][0] + wid * 1024;

    int offA[4], offB[4];
    #pragma unroll
    for (int m = 0; m < 4; m++) {
        int r = waveM + m * 16 + (lane & 15);
        offA[m] = (r * BK + (((lane >> 4) ^ ((r >> 1) & 3)) << 3)) * 2;
    }
    #pragma unroll
    for (int n = 0; n < 4; n++) {
        int r = waveN + n * 16 + (lane & 15);
        offB[n] = (r * BK + (((lane >> 4) ^ ((r >> 1) & 3)) << 3)) * 2;
    }

    float V0[16], V1[16];
    int I0[16], I1[16];
    #pragma unroll
    for (int q = 0; q < 16; q++) {
        V0[q] = INFINITY; V1[q] = INFINITY;
        I0[q] = 0x7fffffff; I1[q] = 0x7fffffff;
    }

#define STG(buf, k0)                                                                       \
    do {                                                                                   \
        char* a_ = ldsA + (buf) * 8192;                                                    \
        char* b_ = ldsB + (buf) * 8192;                                                    \
        __builtin_amdgcn_global_load_lds((CGV*)(aSrc0 + (k0)), (LDSV*)a_, 16, 0, 0);       \
        __builtin_amdgcn_global_load_lds((CGV*)(aSrc1 + (k0)), (LDSV*)(a_ + 4096), 16, 0, 0); \
        __builtin_amdgcn_global_load_lds((CGV*)(bSrc0 + (k0)), (LDSV*)b_, 16, 0, 0);       \
        __builtin_amdgcn_global_load_lds((CGV*)(bSrc1 + (k0)), (LDSV*)(b_ + 4096), 16, 0, 0); \
    } while (0)

#define CMP(buf)                                                                           \
    do {                                                                                   \
        const char* ab_ = (const char*)&As[0][0] + (buf) * 8192;                           \
        const char* bb_ = (const char*)&Bs[0][0] + (buf) * 8192;                           \
        bh8 af[4], bf[4];                                                                  \
        _Pragma("unroll")                                                                  \
        for (int m = 0; m < 4; m++) af[m] = *(const bh8*)(ab_ + offA[m]);                  \
        _Pragma("unroll")                                                                  \
        for (int n = 0; n < 4; n++) bf[n] = *(const bh8*)(bb_ + offB[n]);                  \
        _Pragma("unroll")                                                                  \
        for (int m = 0; m < 4; m++)                                                        \
            _Pragma("unroll")                                                              \
            for (int n = 0; n < 4; n++)                                                    \
                acc[m][n] = __builtin_amdgcn_mfma_f32_16x16x32_bf16(af[m], bf[n],          \
                                                                    acc[m][n], 0, 0, 0);   \
    } while (0)

#define RLD(k0)                                                                            \
    do {                                                                                   \
        ra0 = *(const uint4*)(aSrc0 + (k0)); ra1 = *(const uint4*)(aSrc1 + (k0));          \
        rb0 = *(const uint4*)(bSrc0 + (k0)); rb1 = *(const uint4*)(bSrc1 + (k0));          \
    } while (0)

#define RWR(buf)                                                                           \
    do {                                                                                   \
        char* a_ = (char*)&As[0][0] + (buf) * 8192;                                        \
        char* b_ = (char*)&Bs[0][0] + (buf) * 8192;                                        \
        *(uint4*)(a_ + tid * 16) = ra0; *(uint4*)(a_ + 4096 + tid * 16) = ra1;             \
        *(uint4*)(b_ + tid * 16) = rb0; *(uint4*)(b_ + 4096 + tid * 16) = rb1;             \
    } while (0)

    #pragma unroll 1
    for (int c = 0; c < cpb; ++c) {
        const int colBase = (MODE == 2) ? 0 : (colBase0 + c * BN);
        const unsigned short* bSrc0 = wh + (size_t)(colBase + rr) * KP + csw * 8;
        const unsigned short* bSrc1 = bSrc0 + (size_t)64 * KP;

        fx4 acc[4][4];
        #pragma unroll
        for (int m = 0; m < 4; m++)
            #pragma unroll
            for (int n = 0; n < 4; n++) acc[m][n] = (fx4)0.f;

        if constexpr (MODE != 3) {
            // ring pipeline: 2 stages in flight, counted vmcnt
            STG(0, 0);
            STG(1, BK);
            #pragma unroll
            for (int t = 0; t < KT; ++t) {
                if (t < KT - 1) { asm volatile("s_waitcnt vmcnt(4)" ::: "memory"); }
                else            { asm volatile("s_waitcnt vmcnt(0)" ::: "memory"); }
                __builtin_amdgcn_s_barrier();
                if (t + 2 < KT) STG((t + 2) % 3, (t + 2) * BK);
                if constexpr (MODE == 0) CMP(t % 3);
            }
        } else {
            // reg-staged 2-buffer, compiler-managed waits
            uint4 ra0, ra1, rb0, rb1;
            RLD(0);
            RWR(0);
            __syncthreads();
            #pragma unroll
            for (int t = 0; t < KT; ++t) {
                if (t + 1 < KT) RLD((t + 1) * BK);
                CMP(t & 1);
                __syncthreads();
                if (t + 1 < KT) { RWR((t + 1) & 1); __syncthreads(); }
            }
        }

        if constexpr (MODE == 0 || MODE == 3) {
            const int cb = colBase + waveN + (lane & 15);
            #pragma unroll
            for (int n = 0; n < 4; n++) {
                const float wq = wsq[cb + n * 16];
                const int ci = cb + n * 16;
                #pragma unroll
                for (int m = 0; m < 4; m++)
                    #pragma unroll
                    for (int r = 0; r < 4; r++) {
                        float dv = wq - 2.f * acc[m][n][r];
                        top2_insert(dv, ci, V0[m * 4 + r], I0[m * 4 + r],
                                    V1[m * 4 + r], I1[m * 4 + r]);
                    }
            }
        }
        __syncthreads();
    }

#undef STG
#undef CMP
#undef RLD
#undef RWR

    if constexpr (MODE == 0 || MODE == 3) {
        #pragma unroll
        for (int q = 0; q < 16; q++) {
            float v0 = V0[q], v1 = V1[q];
            int i0 = I0[q], i1 = I1[q];
            #pragma unroll
            for (int mask = 1; mask < 16; mask <<= 1) {
                float w0 = __shfl_xor(v0, mask); int j0 = __shfl_xor(i0, mask);
                float w1 = __shfl_xor(v1, mask); int j1 = __shfl_xor(i1, mask);
                top2_insert(w0, j0, v0, i0, v1, i1);
                top2_insert(w1, j1, v0, i0, v1, i1);
            }
            if ((lane & 15) == 0) {
                int m = q >> 2, r = q & 3;
                int row_local = waveM + m * 16 + (lane >> 4) * 4 + r;
                red[row_local][wid & 1] =
                    make_float4(v0, __int_as_float(i0), v1, __int_as_float(i1));
            }
        }
        __syncthreads();
        if (tid < BM) {
            float4 pa = red[tid][0], pb = red[tid][1];
            float v0 = pa.x, v1 = pa.z;
            int i0 = __float_as_int(pa.y), i1 = __float_as_int(pa.w);
            top2_insert(pb.x, __float_as_int(pb.y), v0, i0, v1, i1);
            top2_insert(pb.z, __float_as_int(pb.w), v0, i0, v1, i1);
            partial[(size_t)(rowBase + tid) * gx + bx] =
                make_float4(v0, __int_as_float(i0), v1, __int_as_float(i1));
        }
    } else {
        // keep staged LDS observably live
        __syncthreads();
        if (tid == 0) {
            volatile float* lv = (volatile float*)&As[0][0];
            partial[L] = make_float4(lv[0], 0.f, 0.f, 0.f);
        }
    }
}

// ---------------------------------------------------------------------------
// Round-3 kernel (verbatim; measured 444 us) — produces the REAL partials.
// ---------------------------------------------------------------------------
__global__ __launch_bounds__(256, 2) void dist_r3_kernel(
    const unsigned short* __restrict__ xh, const unsigned short* __restrict__ wh,
    const float* __restrict__ wsq, float4* __restrict__ partial,
    int gx, int cpb) {
    __shared__ __align__(16) unsigned short As[2][BM * BK];
    __shared__ __align__(16) unsigned short Bs[2][BM * BK];
    __shared__ float4 red[BM][2];

    const int tid = threadIdx.x;
    const int lane = tid & 63;
    const int wid = tid >> 6;
    const int waveM = (wid >> 1) * 64;
    const int waveN = (wid & 1) * 64;

    const int L = blockIdx.x + gx * blockIdx.y;
    const int G = (L & 7) * (gx * 4) + (L >> 3);
    const int bx = G >> 5;
    const int by = G & 31;
    const int rowBase = by * BM;
    const int colBase0 = bx * (cpb * BN);

    const int rr = tid >> 2;
    const int csw = (tid & 3) ^ ((rr >> 1) & 3);
    const unsigned short* aSrc0 = xh + (size_t)(rowBase + rr) * KP + csw * 8;
    const unsigned short* aSrc1 = aSrc0 + (size_t)64 * KP;

    char* ldsA0 = (char*)&As[0][0] + wid * 1024;
    char* ldsA1 = (char*)&As[1][0] + wid * 1024;
    char* ldsB0 = (char*)&Bs[0][0] + wid * 1024;
    char* ldsB1 = (char*)&Bs[1][0] + wid * 1024;

    int offA[4], offB[4];
    #pragma unroll
    for (int m = 0; m < 4; m++) {
        int r = waveM + m * 16 + (lane & 15);
        offA[m] = r * BK + (((lane >> 4) ^ ((r >> 1) & 3)) << 3);
    }
    #pragma unroll
    for (int n = 0; n < 4; n++) {
        int r = waveN + n * 16 + (lane & 15);
        offB[n] = r * BK + (((lane >> 4) ^ ((r >> 1) & 3)) << 3);
    }

    float V0[16], V1[16];
    int I0[16], I1[16];
    #pragma unroll
    for (int q = 0; q < 16; q++) {
        V0[q] = INFINITY; V1[q] = INFINITY;
        I0[q] = 0x7fffffff; I1[q] = 0x7fffffff;
    }

#define STAGE3(nb, k0)                                                                     \
    do {                                                                                   \
        __builtin_amdgcn_global_load_lds((CGV*)(aSrc0 + (k0)), (LDSV*)(ldsA##nb), 16, 0, 0);        \
        __builtin_amdgcn_global_load_lds((CGV*)(aSrc1 + (k0)), (LDSV*)(ldsA##nb + 4096), 16, 0, 0); \
        __builtin_amdgcn_global_load_lds((CGV*)(bSrc0 + (k0)), (LDSV*)(ldsB##nb), 16, 0, 0);        \
        __builtin_amdgcn_global_load_lds((CGV*)(bSrc1 + (k0)), (LDSV*)(ldsB##nb + 4096), 16, 0, 0); \
    } while (0)

#define COMPUTE3(nb)                                                                       \
    do {                                                                                   \
        bh8 af[4], bf[4];                                                                  \
        _Pragma("unroll")                                                                  \
        for (int m = 0; m < 4; m++) af[m] = *(const bh8*)&As[nb][offA[m]];                 \
        _Pragma("unroll")                                                                  \
        for (int n = 0; n < 4; n++) bf[n] = *(const bh8*)&Bs[nb][offB[n]];                 \
        _Pragma("unroll")                                                                  \
        for (int m = 0; m < 4; m++)                                                        \
            _Pragma("unroll")                                                              \
            for (int n = 0; n < 4; n++)                                                    \
                acc[m][n] = __builtin_amdgcn_mfma_f32_16x16x32_bf16(af[m], bf[n],          \
                                                                    acc[m][n], 0, 0, 0);   \
    } while (0)

    #pragma unroll 1
    for (int c = 0; c < cpb; ++c) {
        const int colBase = colBase0 + c * BN;
        const unsigned short* bSrc0 = wh + (size_t)(colBase + rr) * KP + csw * 8;
        const unsigned short* bSrc1 = bSrc0 + (size_t)64 * KP;

        fx4 acc[4][4];
        #pragma unroll
        for (int m = 0; m < 4; m++)
            #pragma unroll
            for (int n = 0; n < 4; n++) acc[m][n] = (fx4)0.f;

        STAGE3(0, 0);
        asm volatile("s_waitcnt vmcnt(0)" ::: "memory");
        __builtin_amdgcn_s_barrier();
        #pragma unroll 1
        for (int t = 0; t < KT - 1; t += 2) {
            STAGE3(1, (t + 1) * BK);
            COMPUTE3(0);
            asm volatile("s_waitcnt vmcnt(0)" ::: "memory");
            __builtin_amdgcn_s_barrier();
            STAGE3(0, (t + 2) * BK);
            COMPUTE3(1);
            asm volatile("s_waitcnt vmcnt(0)" ::: "memory");
            __builtin_amdgcn_s_barrier();
        }
        COMPUTE3(0);

        const int cb = colBase + waveN + (lane & 15);
        #pragma unroll
        for (int n = 0; n < 4; n++) {
            const float wq = wsq[cb + n * 16];
            const int ci = cb + n * 16;
            #pragma unroll
            for (int m = 0; m < 4; m++)
                #pragma unroll
                for (int r = 0; r < 4; r++) {
                    float dv = wq - 2.f * acc[m][n][r];
                    top2_insert(dv, ci, V0[m * 4 + r], I0[m * 4 + r],
                                V1[m * 4 + r], I1[m * 4 + r]);
                }
        }
        __syncthreads();
    }

#undef STAGE3
#undef COMPUTE3

    #pragma unroll
    for (int q = 0; q < 16; q++) {
        float v0 = V0[q], v1 = V1[q];
        int i0 = I0[q], i1 = I1[q];
        #pragma unroll
        for (int mask = 1; mask < 16; mask <<= 1) {
            float w0 = __shfl_xor(v0, mask); int j0 = __shfl_xor(i0, mask);
            float w1 = __shfl_xor(v1, mask); int j1 = __shfl_xor(i1, mask);
            top2_insert(w0, j0, v0, i0, v1, i1);
            top2_insert(w1, j1, v0, i0, v1, i1);
        }
        if ((lane & 15) == 0) {
            int m = q >> 2, r = q & 3;
            int row_local = waveM + m * 16 + (lane >> 4) * 4 + r;
            red[row_local][wid & 1] =
                make_float4(v0, __int_as_float(i0), v1, __int_as_float(i1));
        }
    }
    __syncthreads();
    if (tid < BM) {
        float4 pa = red[tid][0], pb = red[tid][1];
        float v0 = pa.x, v1 = pa.z;
        int i0 = __float_as_int(pa.y), i1 = __float_as_int(pa.w);
        top2_insert(pb.x, __float_as_int(pb.y), v0, i0, v1, i1);
        top2_insert(pb.z, __float_as_int(pb.w), v0, i0, v1, i1);
        partial[(size_t)(rowBase + tid) * gx + bx] =
            make_float4(v0, __int_as_float(i0), v1, __int_as_float(i1));
    }
}

// ---------------------------------------------------------------------------
__global__ __launch_bounds__(256) void rescore_kernel(const float* __restrict__ x,
                                                      const float* __restrict__ w,
                                                      const float4* __restrict__ partial,
                                                      float* __restrict__ out, int ng) {
    int wid = threadIdx.x >> 6, lane = threadIdx.x & 63;
    int row = blockIdx.x * 4 + wid;
    __shared__ int s_cnt[4];
    __shared__ int s_cand[4][64];

    const float4* part = partial + (size_t)row * ng;

    float bv = INFINITY;
    for (int c = lane; c < ng; c += 64) bv = fminf(bv, part[c].x);
    #pragma unroll
    for (int mask = 1; mask < 64; mask <<= 1) bv = fminf(bv, __shfl_xor(bv, mask));
    float thr = bv + MARGIN;

    if (lane == 0) s_cnt[wid] = 0;
    __syncthreads();
    for (int c = lane; c < ng; c += 64) {
        float4 p = part[c];
        if (p.x <= thr) {
            int pos = atomicAdd(&s_cnt[wid], 1);
            if (pos < 64) s_cand[wid][pos] = __float_as_int(p.y);
        }
        if (p.z <= thr) {
            int pos = atomicAdd(&s_cnt[wid], 1);
            if (pos < 64) s_cand[wid][pos] = __float_as_int(p.w);
        }
    }
    __syncthreads();
    int cnt = s_cnt[wid]; if (cnt > 64) cnt = 64;

    double bd = INFINITY; int bi = 0x7fffffff;
    for (int c = 0; c < cnt; c++) {
        int idx = s_cand[wid][c];
        const float* wr = w + (size_t)idx * D;
        const float* xr = x + (size_t)row * D;
        double s = 0.0;
        for (int d = lane; d < D; d += 64) {
            double wv = (double)wr[d];
            s += wv * (wv - 2.0 * (double)xr[d]);
        }
        #pragma unroll
        for (int mask = 1; mask < 64; mask <<= 1) s += __shfl_xor(s, mask);
        if (s < bd || (s == bd && idx < bi)) { bd = s; bi = idx; }
    }

    const float4* src = (const float4*)(w + (size_t)bi * D);
    float4* dst = (float4*)(out + (size_t)row * D);
    for (int i = lane; i < D / 4; i += 64) dst[i] = src[i];
}

// ---------------------------------------------------------------------------
extern "C" void kernel_launch(void* const* d_in, const int* in_sizes, int n_in,
                              void* d_out, int out_size, void* d_ws, size_t ws_size,
                              hipStream_t stream) {
    const float* x = (const float*)d_in[0];
    const float* w = (const float*)d_in[1];
    float* out = (float*)d_out;

    const size_t off_xh = 0;
    const size_t off_wh = off_xh + (size_t)BATCH * KP * 2;
    const size_t off_wsq = off_wh + (size_t)NPAD * KP * 2;
    const size_t off_part = off_wsq + (size_t)NPAD * 4;

    int gxv = 80, cpbv = 1;
    if (ws_size < off_part + (size_t)BATCH * 80 * 16) { gxv = 20; cpbv = 4; }

    unsigned short* xh = (unsigned short*)((char*)d_ws + off_xh);
    unsigned short* wh = (unsigned short*)((char*)d_ws + off_wh);
    float* wsq = (float*)((char*)d_ws + off_wsq);
    float4* partial = (float4*)((char*)d_ws + off_part);

    hipLaunchKernelGGL(convert_x_kernel, dim3(BATCH), dim3(256), 0, stream, x, xh);
    hipLaunchKernelGGL(convert_w_kernel, dim3(NPAD), dim3(256), 0, stream, w, wh, wsq);

    // --- ablation dispatches (scratch writes into partial region) ---
    hipLaunchKernelGGL(dist_ablate_kernel<0>, dim3(gxv, 32), dim3(256), 0, stream,
                       xh, wh, wsq, partial, gxv, cpbv);
    hipLaunchKernelGGL(dist_ablate_kernel<1>, dim3(gxv, 32), dim3(256), 0, stream,
                       xh, wh, wsq, partial, gxv, cpbv);
    hipLaunchKernelGGL(dist_ablate_kernel<2>, dim3(gxv, 32), dim3(256), 0, stream,
                       xh, wh, wsq, partial, gxv, cpbv);
    hipLaunchKernelGGL(dist_ablate_kernel<3>, dim3(gxv, 32), dim3(256), 0, stream,
                       xh, wh, wsq, partial, gxv, cpbv);

    // --- real result: round-3 kernel overwrites partial[0 .. 4096*20) ---
    hipLaunchKernelGGL(dist_r3_kernel, dim3(20, 32), dim3(256), 0, stream,
                       xh, wh, wsq, partial, 20, 4);
    hipLaunchKernelGGL(rescore_kernel, dim3(BATCH / 4), dim3(256), 0, stream,
                       x, w, partial, out, 20);
}

// Round 7
// 586.467 us; speedup vs baseline: 3.3449x; 3.3449x over previous
//
#include <hip/hip_runtime.h>
#include <math.h>

#define BATCH 4096
#define D 784
#define N 10000

#define KP 800                 // padded K (halves) in staging buffers
#define NPAD 10240             // 40 * 256
#define MARGIN 3.0f

// ---- 256x256 main kernel ----
#define BM2 256
#define BN2 256
#define GX2 40                 // col groups
#define GY2 16                 // row groups

// ---- 128x128 fallback (round-3, proven) ----
#define BM 128
#define BN 128
#define BK 32
#define KT 25

typedef __attribute__((ext_vector_type(8))) short bh8;
typedef __attribute__((ext_vector_type(4))) float fx4;
typedef const __attribute__((address_space(1))) void CGV;
typedef __attribute__((address_space(3))) void LDSV;

static __device__ __forceinline__ unsigned short f2bf(float f) {
    unsigned u = __float_as_uint(f);
    unsigned r = u + 0x7fffu + ((u >> 16) & 1u);
    return (unsigned short)(r >> 16);
}

static __device__ __forceinline__ void top2_insert(float w, int j, float& v0, int& i0,
                                                   float& v1, int& i1) {
    if (w < v0 || (w == v0 && j < i0)) { v1 = v0; i1 = i0; v0 = w; i0 = j; }
    else if (w < v1 || (w == v1 && j < i1)) { v1 = w; i1 = j; }
}

// ---------------------------------------------------------------------------
__global__ __launch_bounds__(256) void convert_x_kernel(const float* __restrict__ x,
                                                        unsigned short* __restrict__ xh) {
    int row = blockIdx.x;
    const float4* xr = (const float4*)(x + (size_t)row * D);
    unsigned short* dst = xh + (size_t)row * KP;
    for (int i = threadIdx.x; i < KP / 4; i += 256) {
        int k = i * 4;
        uint2 o;
        if (k < D) {
            float4 v = xr[i];
            o.x = (unsigned)f2bf(v.x) | ((unsigned)f2bf(v.y) << 16);
            o.y = (unsigned)f2bf(v.z) | ((unsigned)f2bf(v.w) << 16);
        } else { o.x = 0u; o.y = 0u; }
        *(uint2*)(dst + k) = o;
    }
}

__global__ __launch_bounds__(256) void convert_w_kernel(const float* __restrict__ w,
                                                        unsigned short* __restrict__ wh,
                                                        float* __restrict__ wsq) {
    int row = blockIdx.x;
    unsigned short* dst = wh + (size_t)row * KP;
    float s = 0.f;
    if (row < N) {
        const float4* wr = (const float4*)(w + (size_t)row * D);
        for (int i = threadIdx.x; i < KP / 4; i += 256) {
            int k = i * 4;
            uint2 o;
            if (k < D) {
                float4 v = wr[i];
                s += v.x * v.x + v.y * v.y + v.z * v.z + v.w * v.w;
                o.x = (unsigned)f2bf(v.x) | ((unsigned)f2bf(v.y) << 16);
                o.y = (unsigned)f2bf(v.z) | ((unsigned)f2bf(v.w) << 16);
            } else { o.x = 0u; o.y = 0u; }
            *(uint2*)(dst + k) = o;
        }
    } else {
        for (int i = threadIdx.x; i < KP / 4; i += 256) {
            uint2 o; o.x = 0u; o.y = 0u;
            *(uint2*)(dst + i * 4) = o;
        }
    }
    __shared__ float sred[4];
    #pragma unroll
    for (int off = 32; off; off >>= 1) s += __shfl_down(s, off);
    if ((threadIdx.x & 63) == 0) sred[threadIdx.x >> 6] = s;
    __syncthreads();
    if (threadIdx.x == 0) {
        float t = sred[0] + sred[1] + sred[2] + sred[3];
        wsq[row] = (row < N) ? t : INFINITY;
    }
}

// ---------------------------------------------------------------------------
// 256x256 MFMA distance kernel. 8 waves (2M x 4N), BK=64, 13 steps
// (12 full + 1 half), double-buffered global_load_lds, issue-early/wait-late,
// XOR seg-swizzle (uniform bank load), top-2 fold once per block from acc.
// ---------------------------------------------------------------------------
__global__ __launch_bounds__(512, 2) void dist_mfma256_kernel(
    const unsigned short* __restrict__ xh, const unsigned short* __restrict__ wh,
    const float* __restrict__ wsq, float4* __restrict__ partial) {
    __shared__ __align__(16) char smem[131072];   // buf b: A @ b*65536, B @ +32768

    const int tid = threadIdx.x;
    const int lane = tid & 63;
    const int wid = tid >> 6;            // 0..7
    const int waveM = (wid >> 2) * 128;  // 0,128
    const int wn = wid & 3;              // 0..3
    const int waveN = wn * 64;

    // XCD remap: 640 blocks, bijective; XCD owns 2 row-panels, sweeps bx
    const int L = blockIdx.x + GX2 * blockIdx.y;
    const int xcd = L & 7;
    const int sg = L >> 3;               // 0..79
    const int bx = sg >> 1;              // 0..39
    const int by = xcd * 2 + (sg & 1);   // 0..15
    const int rowBase = by * BM2;
    const int colBase = bx * BN2;

    // staging: thread t -> row rr = t>>3 (+j*64), phys seg t&7,
    // logical seg = (t&7) ^ (rr&7)  (row&7 invariant under +64)
    const int rr = tid >> 3;
    const int ps = tid & 7;
    const int ls = ps ^ (rr & 7);
    const unsigned short* aS = xh + (size_t)(rowBase + rr) * KP + ls * 8;
    const unsigned short* bS = wh + (size_t)(colBase + rr) * KP + ls * 8;
    // tail (k 768..799): clamp logical seg >=4 to a safe in-bounds address;
    // those phys slots hold garbage the tail compute never reads.
    const int lsc = (ls < 4) ? ls : 3;
    const unsigned short* aT = xh + (size_t)(rowBase + rr) * KP + 768 + lsc * 8;
    const unsigned short* bT = wh + (size_t)(colBase + rr) * KP + 768 + lsc * 8;

    // per-wave LDS dest bases: call j covers rows j*64; wave w rows w*8..w*8+7
    char* const ldsA = smem + wid * 1024;
    char* const ldsB = smem + 32768 + wid * 1024;

    fx4 acc[8][4];
    #pragma unroll
    for (int m = 0; m < 8; m++)
        #pragma unroll
        for (int n = 0; n < 4; n++) acc[m][n] = (fx4)0.f;

#define STAGE2(buf, k0, Asrc, Bsrc)                                                   \
    do {                                                                              \
        char* a_ = ldsA + (buf) * 65536;                                              \
        char* b_ = ldsB + (buf) * 65536;                                              \
        _Pragma("unroll")                                                             \
        for (int j = 0; j < 4; j++) {                                                 \
            __builtin_amdgcn_global_load_lds((CGV*)(Asrc + (k0) + (size_t)j * 64 * KP), \
                                             (LDSV*)(a_ + j * 8192), 16, 0, 0);       \
            __builtin_amdgcn_global_load_lds((CGV*)(Bsrc + (k0) + (size_t)j * 64 * KP), \
                                             (LDSV*)(b_ + j * 8192), 16, 0, 0);       \
        }                                                                             \
    } while (0)

#define KSUB(buf, s)                                                                  \
    do {                                                                              \
        const char* A_ = smem + (buf) * 65536;                                        \
        const char* B_ = smem + (buf) * 65536 + 32768;                                \
        bh8 af[8], bf[4];                                                             \
        _Pragma("unroll")                                                             \
        for (int m = 0; m < 8; m++) {                                                 \
            int row = waveM + m * 16 + (lane & 15);                                   \
            int seg = ((s) * 4 + (lane >> 4)) ^ (lane & 7);                           \
            af[m] = *(const bh8*)(A_ + row * 128 + seg * 16);                         \
        }                                                                             \
        _Pragma("unroll")                                                             \
        for (int n = 0; n < 4; n++) {                                                 \
            int row = waveN + n * 16 + (lane & 15);                                   \
            int seg = ((s) * 4 + (lane >> 4)) ^ (lane & 7);                           \
            bf[n] = *(const bh8*)(B_ + row * 128 + seg * 16);                         \
        }                                                                             \
        _Pragma("unroll")                                                             \
        for (int m = 0; m < 8; m++)                                                   \
            _Pragma("unroll")                                                         \
            for (int n = 0; n < 4; n++)                                               \
                acc[m][n] = __builtin_amdgcn_mfma_f32_16x16x32_bf16(af[m], bf[n],     \
                                                                    acc[m][n], 0, 0, 0); \
    } while (0)

    STAGE2(0, 0, aS, bS);
    asm volatile("s_waitcnt vmcnt(0)" ::: "memory");
    __builtin_amdgcn_s_barrier();

    #pragma unroll
    for (int t = 0; t < 12; ++t) {
        if (t < 11) STAGE2((t + 1) & 1, (t + 1) * 64, aS, bS);   // issue-early
        else        STAGE2(0, 0, aT, bT);                        // stage tail
        KSUB(t & 1, 0);
        KSUB(t & 1, 1);
        asm volatile("s_waitcnt vmcnt(0)" ::: "memory");         // wait-late
        __builtin_amdgcn_s_barrier();
    }
    KSUB(0, 0);          // tail step: k 768..799 only (logical segs 0..3)
    __syncthreads();     // all LDS reads done before red aliases smem

#undef STAGE2
#undef KSUB

    // ---- fold: per-row top-2 over this block's 256 cols, from acc ----
    float4* red4 = (float4*)smem;   // red[row][wn] = red4[row*4 + wn]
    const int colT = colBase + waveN + (lane & 15);
    float wq[4]; int ci[4];
    #pragma unroll
    for (int n = 0; n < 4; n++) { ci[n] = colT + n * 16; wq[n] = wsq[ci[n]]; }

    #pragma unroll
    for (int m = 0; m < 8; m++) {
        #pragma unroll
        for (int r = 0; r < 4; r++) {
            float v0 = INFINITY, v1 = INFINITY;
            int i0 = 0x7fffffff, i1 = 0x7fffffff;
            #pragma unroll
            for (int n = 0; n < 4; n++) {
                float dv = wq[n] - 2.f * acc[m][n][r];
                top2_insert(dv, ci[n], v0, i0, v1, i1);
            }
            #pragma unroll
            for (int mask = 1; mask < 16; mask <<= 1) {
                float w0 = __shfl_xor(v0, mask); int j0 = __shfl_xor(i0, mask);
                float w1 = __shfl_xor(v1, mask); int j1 = __shfl_xor(i1, mask);
                top2_insert(w0, j0, v0, i0, v1, i1);
                top2_insert(w1, j1, v0, i0, v1, i1);
            }
            if ((lane & 15) == 0) {
                int row_local = waveM + m * 16 + (lane >> 4) * 4 + r;
                red4[row_local * 4 + wn] =
                    make_float4(v0, __int_as_float(i0), v1, __int_as_float(i1));
            }
        }
    }
    __syncthreads();
    if (tid < BM2) {
        float4 p0 = red4[tid * 4 + 0];
        float v0 = p0.x, v1 = p0.z;
        int i0 = __float_as_int(p0.y), i1 = __float_as_int(p0.w);
        #pragma unroll
        for (int g = 1; g < 4; g++) {
            float4 p = red4[tid * 4 + g];
            top2_insert(p.x, __float_as_int(p.y), v0, i0, v1, i1);
            top2_insert(p.z, __float_as_int(p.w), v0, i0, v1, i1);
        }
        partial[(size_t)(rowBase + tid) * GX2 + bx] =
            make_float4(v0, __int_as_float(i0), v1, __int_as_float(i1));
    }
}

// ---------------------------------------------------------------------------
// Fallback: round-3 128x128 kernel (verbatim, proven 444 us), gx=20/cpb=4.
// ---------------------------------------------------------------------------
__global__ __launch_bounds__(256, 2) void dist_r3_kernel(
    const unsigned short* __restrict__ xh, const unsigned short* __restrict__ wh,
    const float* __restrict__ wsq, float4* __restrict__ partial,
    int gx, int cpb) {
    __shared__ __align__(16) unsigned short As[2][BM * BK];
    __shared__ __align__(16) unsigned short Bs[2][BM * BK];
    __shared__ float4 red[BM][2];

    const int tid = threadIdx.x;
    const int lane = tid & 63;
    const int wid = tid >> 6;
    const int waveM = (wid >> 1) * 64;
    const int waveN = (wid & 1) * 64;

    const int L = blockIdx.x + gx * blockIdx.y;
    const int G = (L & 7) * (gx * 4) + (L >> 3);
    const int bx = G >> 5;
    const int by = G & 31;
    const int rowBase = by * BM;
    const int colBase0 = bx * (cpb * BN);

    const int rr = tid >> 2;
    const int csw = (tid & 3) ^ ((rr >> 1) & 3);
    const unsigned short* aSrc0 = xh + (size_t)(rowBase + rr) * KP + csw * 8;
    const unsigned short* aSrc1 = aSrc0 + (size_t)64 * KP;

    char* ldsA0 = (char*)&As[0][0] + wid * 1024;
    char* ldsA1 = (char*)&As[1][0] + wid * 1024;
    char* ldsB0 = (char*)&Bs[0][0] + wid * 1024;
    char* ldsB1 = (char*)&Bs[1][0] + wid * 1024;

    int offA[4], offB[4];
    #pragma unroll
    for (int m = 0; m < 4; m++) {
        int r = waveM + m * 16 + (lane & 15);
        offA[m] = r * BK + (((lane >> 4) ^ ((r >> 1) & 3)) << 3);
    }
    #pragma unroll
    for (int n = 0; n < 4; n++) {
        int r = waveN + n * 16 + (lane & 15);
        offB[n] = r * BK + (((lane >> 4) ^ ((r >> 1) & 3)) << 3);
    }

    float V0[16], V1[16];
    int I0[16], I1[16];
    #pragma unroll
    for (int q = 0; q < 16; q++) {
        V0[q] = INFINITY; V1[q] = INFINITY;
        I0[q] = 0x7fffffff; I1[q] = 0x7fffffff;
    }

#define STAGE3(nb, k0)                                                                     \
    do {                                                                                   \
        __builtin_amdgcn_global_load_lds((CGV*)(aSrc0 + (k0)), (LDSV*)(ldsA##nb), 16, 0, 0);        \
        __builtin_amdgcn_global_load_lds((CGV*)(aSrc1 + (k0)), (LDSV*)(ldsA##nb + 4096), 16, 0, 0); \
        __builtin_amdgcn_global_load_lds((CGV*)(bSrc0 + (k0)), (LDSV*)(ldsB##nb), 16, 0, 0);        \
        __builtin_amdgcn_global_load_lds((CGV*)(bSrc1 + (k0)), (LDSV*)(ldsB##nb + 4096), 16, 0, 0); \
    } while (0)

#define COMPUTE3(nb)                                                                       \
    do {                                                                                   \
        bh8 af[4], bf[4];                                                                  \
        _Pragma("unroll")                                                                  \
        for (int m = 0; m < 4; m++) af[m] = *(const bh8*)&As[nb][offA[m]];                 \
        _Pragma("unroll")                                                                  \
        for (int n = 0; n < 4; n++) bf[n] = *(const bh8*)&Bs[nb][offB[n]];                 \
        _Pragma("unroll")                                                                  \
        for (int m = 0; m < 4; m++)                                                        \
            _Pragma("unroll")                                                              \
            for (int n = 0; n < 4; n++)                                                    \
                acc[m][n] = __builtin_amdgcn_mfma_f32_16x16x32_bf16(af[m], bf[n],          \
                                                                    acc[m][n], 0, 0, 0);   \
    } while (0)

    #pragma unroll 1
    for (int c = 0; c < cpb; ++c) {
        const int colBase = colBase0 + c * BN;
        const unsigned short* bSrc0 = wh + (size_t)(colBase + rr) * KP + csw * 8;
        const unsigned short* bSrc1 = bSrc0 + (size_t)64 * KP;

        fx4 acc[4][4];
        #pragma unroll
        for (int m = 0; m < 4; m++)
            #pragma unroll
            for (int n = 0; n < 4; n++) acc[m][n] = (fx4)0.f;

        STAGE3(0, 0);
        asm volatile("s_waitcnt vmcnt(0)" ::: "memory");
        __builtin_amdgcn_s_barrier();
        #pragma unroll 1
        for (int t = 0; t < KT - 1; t += 2) {
            STAGE3(1, (t + 1) * BK);
            COMPUTE3(0);
            asm volatile("s_waitcnt vmcnt(0)" ::: "memory");
            __builtin_amdgcn_s_barrier();
            STAGE3(0, (t + 2) * BK);
            COMPUTE3(1);
            asm volatile("s_waitcnt vmcnt(0)" ::: "memory");
            __builtin_amdgcn_s_barrier();
        }
        COMPUTE3(0);

        const int cb = colBase + waveN + (lane & 15);
        #pragma unroll
        for (int n = 0; n < 4; n++) {
            const float wq = wsq[cb + n * 16];
            const int ci = cb + n * 16;
            #pragma unroll
            for (int m = 0; m < 4; m++)
                #pragma unroll
                for (int r = 0; r < 4; r++) {
                    float dv = wq - 2.f * acc[m][n][r];
                    top2_insert(dv, ci, V0[m * 4 + r], I0[m * 4 + r],
                                V1[m * 4 + r], I1[m * 4 + r]);
                }
        }
        __syncthreads();
    }

#undef STAGE3
#undef COMPUTE3

    #pragma unroll
    for (int q = 0; q < 16; q++) {
        float v0 = V0[q], v1 = V1[q];
        int i0 = I0[q], i1 = I1[q];
        #pragma unroll
        for (int mask = 1; mask < 16; mask <<= 1) {
            float w0 = __shfl_xor(v0, mask); int j0 = __shfl_xor(i0, mask);
            float w1 = __shfl_xor(v1, mask); int j1 = __shfl_xor(i1, mask);
            top2_insert(w0, j0, v0, i0, v1, i1);
            top2_insert(w1, j1, v0, i0, v1, i1);
        }
        if ((lane & 15) == 0) {
            int m = q >> 2, r = q & 3;
            int row_local = waveM + m * 16 + (lane >> 4) * 4 + r;
            red[row_local][wid & 1] =
                make_float4(v0, __int_as_float(i0), v1, __int_as_float(i1));
        }
    }
    __syncthreads();
    if (tid < BM) {
        float4 pa = red[tid][0], pb = red[tid][1];
        float v0 = pa.x, v1 = pa.z;
        int i0 = __float_as_int(pa.y), i1 = __float_as_int(pa.w);
        top2_insert(pb.x, __float_as_int(pb.y), v0, i0, v1, i1);
        top2_insert(pb.z, __float_as_int(pb.w), v0, i0, v1, i1);
        partial[(size_t)(rowBase + tid) * gx + bx] =
            make_float4(v0, __int_as_float(i0), v1, __int_as_float(i1));
    }
}

// ---------------------------------------------------------------------------
// Rescue: fp64 rescore of all candidates within MARGIN of approx global min.
// ---------------------------------------------------------------------------
__global__ __launch_bounds__(256) void rescore_kernel(const float* __restrict__ x,
                                                      const float* __restrict__ w,
                                                      const float4* __restrict__ partial,
                                                      float* __restrict__ out, int ng) {
    int wid = threadIdx.x >> 6, lane = threadIdx.x & 63;
    int row = blockIdx.x * 4 + wid;
    __shared__ int s_cnt[4];
    __shared__ int s_cand[4][64];

    const float4* part = partial + (size_t)row * ng;

    float bv = INFINITY;
    for (int c = lane; c < ng; c += 64) bv = fminf(bv, part[c].x);
    #pragma unroll
    for (int mask = 1; mask < 64; mask <<= 1) bv = fminf(bv, __shfl_xor(bv, mask));
    float thr = bv + MARGIN;

    if (lane == 0) s_cnt[wid] = 0;
    __syncthreads();
    for (int c = lane; c < ng; c += 64) {
        float4 p = part[c];
        if (p.x <= thr) {
            int pos = atomicAdd(&s_cnt[wid], 1);
            if (pos < 64) s_cand[wid][pos] = __float_as_int(p.y);
        }
        if (p.z <= thr) {
            int pos = atomicAdd(&s_cnt[wid], 1);
            if (pos < 64) s_cand[wid][pos] = __float_as_int(p.w);
        }
    }
    __syncthreads();
    int cnt = s_cnt[wid]; if (cnt > 64) cnt = 64;

    double bd = INFINITY; int bi = 0x7fffffff;
    for (int c = 0; c < cnt; c++) {
        int idx = s_cand[wid][c];
        const float* wr = w + (size_t)idx * D;
        const float* xr = x + (size_t)row * D;
        double s = 0.0;
        for (int d = lane; d < D; d += 64) {
            double wv = (double)wr[d];
            s += wv * (wv - 2.0 * (double)xr[d]);
        }
        #pragma unroll
        for (int mask = 1; mask < 64; mask <<= 1) s += __shfl_xor(s, mask);
        if (s < bd || (s == bd && idx < bi)) { bd = s; bi = idx; }
    }

    const float4* src = (const float4*)(w + (size_t)bi * D);
    float4* dst = (float4*)(out + (size_t)row * D);
    for (int i = lane; i < D / 4; i += 64) dst[i] = src[i];
}

// ---------------------------------------------------------------------------
extern "C" void kernel_launch(void* const* d_in, const int* in_sizes, int n_in,
                              void* d_out, int out_size, void* d_ws, size_t ws_size,
                              hipStream_t stream) {
    const float* x = (const float*)d_in[0];
    const float* w = (const float*)d_in[1];
    float* out = (float*)d_out;

    const size_t off_xh = 0;
    const size_t off_wh = off_xh + (size_t)BATCH * KP * 2;     // 6,553,600
    const size_t off_wsq = off_wh + (size_t)NPAD * KP * 2;     // +16,384,000
    const size_t off_part = off_wsq + (size_t)NPAD * 4;        // +40,960
    const size_t need256 = off_part + (size_t)BATCH * GX2 * 16; // 25,600,000

    unsigned short* xh = (unsigned short*)((char*)d_ws + off_xh);
    unsigned short* wh = (unsigned short*)((char*)d_ws + off_wh);
    float* wsq = (float*)((char*)d_ws + off_wsq);
    float4* partial = (float4*)((char*)d_ws + off_part);

    hipLaunchKernelGGL(convert_x_kernel, dim3(BATCH), dim3(256), 0, stream, x, xh);
    hipLaunchKernelGGL(convert_w_kernel, dim3(NPAD), dim3(256), 0, stream, w, wh, wsq);

    if (ws_size >= need256) {
        hipLaunchKernelGGL(dist_mfma256_kernel, dim3(GX2, GY2), dim3(512), 0, stream,
                           xh, wh, wsq, partial);
        hipLaunchKernelGGL(rescore_kernel, dim3(BATCH / 4), dim3(256), 0, stream,
                           x, w, partial, out, GX2);
    } else {
        hipLaunchKernelGGL(dist_r3_kernel, dim3(20, 32), dim3(256), 0, stream,
                           xh, wh, wsq, partial, 20, 4);
        hipLaunchKernelGGL(rescore_kernel, dim3(BATCH / 4), dim3(256), 0, stream,
                           x, w, partial, out, 20);
    }
}